// Round 13
// baseline (42.599 us; speedup 1.0000x reference)
//
#include <hip/hip_runtime.h>
#include <math.h>

#define NT 64
#define L_LEN 720
#define NROWS (64 * 321)       // 20544
#define RPW 4                  // rows per wave
#define NBLK (NROWS / RPW)     // 5136

#define LOG2E 1.4426950408889634f
#define LN2   0.6931471805599453f

// ---- DPP wave reductions: pure VALU pipe, no LDS, no lgkmcnt stalls ----
template<int CTRL, int RM>
__device__ __forceinline__ float dpp_add(float x) {
    int t = __builtin_amdgcn_update_dpp(0, __float_as_int(x), CTRL, RM, 0xf, true);
    return x + __int_as_float(t);
}

__device__ __forceinline__ float wave_sum64(float x) {
    x = dpp_add<0x111, 0xf>(x);   // row_shr:1
    x = dpp_add<0x112, 0xf>(x);   // row_shr:2
    x = dpp_add<0x114, 0xf>(x);   // row_shr:4
    x = dpp_add<0x118, 0xf>(x);   // row_shr:8
    x = dpp_add<0x142, 0xa>(x);   // row_bcast:15 -> rows 1,3
    x = dpp_add<0x143, 0xc>(x);   // row_bcast:31 -> rows 2,3 ; lane63 = total
    return __int_as_float(__builtin_amdgcn_readlane(__float_as_int(x), 63));
}

__device__ __forceinline__ float half_sum32(float x) {
    x = dpp_add<0x111, 0xf>(x);
    x = dpp_add<0x112, 0xf>(x);
    x = dpp_add<0x114, 0xf>(x);
    x = dpp_add<0x118, 0xf>(x);
    x = dpp_add<0x142, 0xa>(x);   // lane31 = sum lanes 0..31
    return __int_as_float(__builtin_amdgcn_readlane(__float_as_int(x), 31));
}

// load one row window: x[12*ll-4 .. 12*ll+15] (clamped, 16B-aligned chunks)
__device__ __forceinline__ void load_win(const float* __restrict__ xr, int e0,
                                         float (&xw)[20]) {
#pragma unroll
    for (int q = 0; q < 5; ++q) {
        int e = e0 + 4 * q;
        e = (e < 0) ? 0 : ((e > L_LEN - 4) ? (L_LEN - 4) : e);
        float4 v = *(const float4*)(xr + e);
        xw[4 * q + 0] = v.x; xw[4 * q + 1] = v.y;
        xw[4 * q + 2] = v.z; xw[4 * q + 3] = v.w;
    }
}

__global__ __launch_bounds__(NT, 4) void trend_kernel(
    const float* __restrict__ x,
    const float* __restrict__ cw0, const float* __restrict__ cb0,
    const float* __restrict__ cw1, const float* __restrict__ cb1,
    const float* __restrict__ cw2, const float* __restrict__ cb2,
    const float* __restrict__ cw3, const float* __restrict__ cb3,
    const float* __restrict__ W1, const float* __restrict__ b1,
    const float* __restrict__ W2, const float* __restrict__ b2,
    float* __restrict__ out)
{
    // ONE wave per block; FOUR consecutive rows per wave, ping-pong
    // prefetched windows. All weight/MLP operands hoisted once per wave:
    // the per-row tail is pure VALU (DPP reductions, no memory).
    const int lane = threadIdx.x;                 // 0..63
    const int row0 = blockIdx.x * RPW;

    const int ll = (lane < 60) ? lane : 59;       // lanes 60..63 shadow 59
    const int e0 = 12 * ll - 4;
    const bool active = lane < 60;

    // ---- issue first row's loads immediately
    const float* __restrict__ xr0 = x + (size_t)row0 * L_LEN;
    float xwA[20], xwB[20];
    load_win(xr0, e0, xwA);
    load_win(xr0 + L_LEN, e0, xwB);               // prefetch row1

    // ---- per-wave setup under the load shadow (all uniform / hoisted)
    const float* cws[4] = {cw0, cw1, cw2, cw3};
    const float* cbs[4] = {cb0, cb1, cb2, cb3};
    float w2[4][9], bs2[4];
#pragma unroll
    for (int s = 0; s < 4; ++s) {
        const int k = 3 + 2 * s;
        bs2[s] = cbs[s][0] * LOG2E;
#pragma unroll
        for (int t = 0; t < 9; ++t)
            w2[s][t] = (t < k) ? (cws[s][t] * LOG2E) : 0.0f;
    }
    const int hidx = lane & 31;
    float w1r[4];
#pragma unroll
    for (int s = 0; s < 4; ++s) w1r[s] = W1[s * 32 + hidx];
    const float b1r = b1[hidx];
    const float4 w2r = ((const float4*)W2)[hidx];
    const float b20 = b2[0], b21 = b2[1], b22 = b2[2], b23 = b2[3];

    // ---- per-row compute (tail is pure VALU; output conv from regs)
    auto compute = [&](float (&xw)[20], int row) {
        // pin at USE time (not at issue: keeps the prefetch async)
#pragma unroll
        for (int t = 0; t < 20; ++t) asm volatile("" : "+v"(xw[t]));
        if (lane == 0)  { xw[0] = 0.f; xw[1] = 0.f; xw[2] = 0.f; xw[3] = 0.f; }
        if (lane == 59) { xw[16] = 0.f; xw[17] = 0.f; xw[18] = 0.f; xw[19] = 0.f; }

        float S[4]  = {0.f, 0.f, 0.f, 0.f};
        float Tu[4] = {0.f, 0.f, 0.f, 0.f};
#pragma unroll
        for (int e = 0; e < 12; ++e) {
#pragma unroll
            for (int s = 0; s < 4; ++s) {
                const int k = 3 + 2 * s;
                const int off = 3 - s;            // 4 - k/2
                float u = bs2[s];
#pragma unroll
                for (int t = 0; t < k; ++t)
                    u = fmaf(w2[s][t], xw[e + off + t], u);
                float ev = __builtin_amdgcn_exp2f(u);
                S[s]  += ev;
                Tu[s]  = fmaf(u, ev, Tu[s]);
            }
        }
#pragma unroll
        for (int s = 0; s < 4; ++s) {
            S[s]  = active ? S[s]  : 0.0f;
            Tu[s] = active ? Tu[s] : 0.0f;
        }

        float ent[4];
#pragma unroll
        for (int s = 0; s < 4; ++s) {
            float Sg = wave_sum64(S[s]);
            float Tg = wave_sum64(Tu[s]);
            ent[s] = LN2 * (__builtin_amdgcn_logf(Sg)
                            - Tg * __builtin_amdgcn_rcpf(Sg));
        }

        float h = b1r;
#pragma unroll
        for (int s = 0; s < 4; ++s) h = fmaf(ent[s], w1r[s], h);
        h = fmaxf(h, 0.0f);

        float lg0 = half_sum32(h * w2r.x) + b20;
        float lg1 = half_sum32(h * w2r.y) + b21;
        float lg2 = half_sum32(h * w2r.z) + b22;
        float lg3 = half_sum32(h * w2r.w) + b23;

        float m = fmaxf(fmaxf(lg0, lg1), fmaxf(lg2, lg3));
        float e0w = __expf(lg0 - m), e1w = __expf(lg1 - m);
        float e2w = __expf(lg2 - m), e3w = __expf(lg3 - m);
        float inv = LN2 / (e0w + e1w + e2w + e3w);
        const float wgt[4] = {e0w * inv, e1w * inv, e2w * inv, e3w * inv};

        float Wm[9] = {0,0,0,0,0,0,0,0,0};
        float Bm = 0.f;
#pragma unroll
        for (int s = 0; s < 4; ++s) {
            const int k = 3 + 2 * s;
            const int off = 3 - s;
#pragma unroll
            for (int t = 0; t < k; ++t)
                Wm[off + t] = fmaf(wgt[s], w2[s][t], Wm[off + t]);
            Bm = fmaf(wgt[s], bs2[s], Bm);
        }

        if (active) {
            float* __restrict__ orow = out + (size_t)row * L_LEN + 12 * lane;
#pragma unroll
            for (int q = 0; q < 3; ++q) {
                float4 v;
#pragma unroll
                for (int c = 0; c < 4; ++c) {
                    const int e = 4 * q + c;
                    float acc = Bm;
#pragma unroll
                    for (int j = 0; j < 9; ++j)
                        acc = fmaf(Wm[j], xw[e + j], acc);
                    ((float*)&v)[c] = acc;
                }
                *(float4*)(orow + 4 * q) = v;
            }
        }
    };

    // ping-pong: compute(cur) while the other buffer's loads are in flight
    compute(xwA, row0 + 0);
    load_win(xr0 + 2 * L_LEN, e0, xwA);           // prefetch row2 over row1's tail
    compute(xwB, row0 + 1);
    load_win(xr0 + 3 * L_LEN, e0, xwB);           // prefetch row3 over row2's tail
    compute(xwA, row0 + 2);
    compute(xwB, row0 + 3);
}

extern "C" void kernel_launch(void* const* d_in, const int* in_sizes, int n_in,
                              void* d_out, int out_size, void* d_ws, size_t ws_size,
                              hipStream_t stream) {
    const float* xp  = (const float*)d_in[0];
    const float* cw0 = (const float*)d_in[1];
    const float* cb0 = (const float*)d_in[2];
    const float* cw1 = (const float*)d_in[3];
    const float* cb1 = (const float*)d_in[4];
    const float* cw2 = (const float*)d_in[5];
    const float* cb2 = (const float*)d_in[6];
    const float* cw3 = (const float*)d_in[7];
    const float* cb3 = (const float*)d_in[8];
    const float* W1  = (const float*)d_in[9];
    const float* b1  = (const float*)d_in[10];
    const float* W2  = (const float*)d_in[11];
    const float* b2  = (const float*)d_in[12];
    float* outp = (float*)d_out;

    trend_kernel<<<NBLK, NT, 0, stream>>>(xp, cw0, cb0, cw1, cb1, cw2, cb2,
                                          cw3, cb3, W1, b1, W2, b2, outp);
}

// Round 14
// 33.598 us; speedup vs baseline: 1.2679x; 1.2679x over previous
//
#include <hip/hip_runtime.h>
#include <math.h>

#define NT 64
#define L_LEN 720
#define NROWS (64 * 321)   // 20544

#define LOG2E 1.4426950408889634f
#define LN2   0.6931471805599453f

typedef float f32x2 __attribute__((ext_vector_type(2)));

__device__ __forceinline__ f32x2 pkfma(f32x2 a, f32x2 b, f32x2 c) {
    return __builtin_elementwise_fma(a, b, c);   // -> v_pk_fma_f32
}

// ---- DPP wave reductions: pure VALU pipe, no LDS, no lgkmcnt stalls ----
template<int CTRL, int RM>
__device__ __forceinline__ float dpp_add(float x) {
    int t = __builtin_amdgcn_update_dpp(0, __float_as_int(x), CTRL, RM, 0xf, true);
    return x + __int_as_float(t);
}

__device__ __forceinline__ float wave_sum64(float x) {
    x = dpp_add<0x111, 0xf>(x);   // row_shr:1
    x = dpp_add<0x112, 0xf>(x);   // row_shr:2
    x = dpp_add<0x114, 0xf>(x);   // row_shr:4
    x = dpp_add<0x118, 0xf>(x);   // row_shr:8
    x = dpp_add<0x142, 0xa>(x);   // row_bcast:15 -> rows 1,3
    x = dpp_add<0x143, 0xc>(x);   // row_bcast:31 -> rows 2,3 ; lane63 = total
    return __int_as_float(__builtin_amdgcn_readlane(__float_as_int(x), 63));
}

__device__ __forceinline__ float half_sum32(float x) {
    x = dpp_add<0x111, 0xf>(x);
    x = dpp_add<0x112, 0xf>(x);
    x = dpp_add<0x114, 0xf>(x);
    x = dpp_add<0x118, 0xf>(x);
    x = dpp_add<0x142, 0xa>(x);   // lane31 = sum lanes 0..31
    return __int_as_float(__builtin_amdgcn_readlane(__float_as_int(x), 31));
}

__global__ __launch_bounds__(NT, 4) void trend_kernel(
    const float* __restrict__ x,
    const float* __restrict__ cw0, const float* __restrict__ cb0,
    const float* __restrict__ cw1, const float* __restrict__ cb1,
    const float* __restrict__ cw2, const float* __restrict__ cb2,
    const float* __restrict__ cw3, const float* __restrict__ cb3,
    const float* __restrict__ W1, const float* __restrict__ b1,
    const float* __restrict__ W2, const float* __restrict__ b2,
    float* __restrict__ out)
{
    // ONE wave per block (R12 structure) + PACKED-FP32 conv/accumulate:
    // v_pk_fma_f32 halves the issue count of the FMA-dominated loops.
    const int lane = threadIdx.x;            // 0..63
    const int row  = blockIdx.x;

    const float* __restrict__ xr = x + (size_t)row * L_LEN;

    // ---- loads first (lanes 60..63 shadow lane 59; masked later)
    const int ll = (lane < 60) ? lane : 59;
    const int e0 = 12 * ll - 4;
    float xw[20];
#pragma unroll
    for (int q = 0; q < 5; ++q) {
        int e = e0 + 4 * q;
        e = (e < 0) ? 0 : ((e > L_LEN - 4) ? (L_LEN - 4) : e);   // 16B-aligned
        float4 v = *(const float4*)(xr + e);
        xw[4 * q + 0] = v.x; xw[4 * q + 1] = v.y;
        xw[4 * q + 2] = v.z; xw[4 * q + 3] = v.w;
    }

    // ---- uniform weight setup under the load shadow (LOG2E pre-folded)
    const float* cws[4] = {cw0, cw1, cw2, cw3};
    const float* cbs[4] = {cb0, cb1, cb2, cb3};
    float w2[4][9], bs2[4];
#pragma unroll
    for (int s = 0; s < 4; ++s) {
        const int k = 3 + 2 * s;
        bs2[s] = cbs[s][0] * LOG2E;
#pragma unroll
        for (int t = 0; t < 9; ++t)
            w2[s][t] = (t < k) ? (cws[s][t] * LOG2E) : 0.0f;
    }

    // row-edge zero padding
    if (lane == 0)  { xw[0] = 0.f; xw[1] = 0.f; xw[2] = 0.f; xw[3] = 0.f; }
    if (lane == 59) { xw[16] = 0.f; xw[17] = 0.f; xw[18] = 0.f; xw[19] = 0.f; }

    // pin scalars once (loads happen exactly once)
#pragma unroll
    for (int t = 0; t < 20; ++t) asm volatile("" : "+v"(xw[t]));

    // ---- build even/odd pair views for packed ops
    f32x2 xp[10], xo[9];
#pragma unroll
    for (int i = 0; i < 10; ++i) xp[i] = (f32x2){xw[2 * i], xw[2 * i + 1]};
#pragma unroll
    for (int i = 0; i < 9; ++i)  xo[i] = (f32x2){xw[2 * i + 1], xw[2 * i + 2]};

    // ---- fused packed pass: conv(u) -> 2^u -> accumulate S, Tu
    // element pair (2j, 2j+1); tap t reads pair starting at st = 2j+off+t
    f32x2 Spk[4]  = {{0.f,0.f},{0.f,0.f},{0.f,0.f},{0.f,0.f}};
    f32x2 Tpk[4]  = {{0.f,0.f},{0.f,0.f},{0.f,0.f},{0.f,0.f}};
#pragma unroll
    for (int j = 0; j < 6; ++j) {
#pragma unroll
        for (int s = 0; s < 4; ++s) {
            const int k = 3 + 2 * s;
            const int off = 3 - s;              // 4 - k/2
            f32x2 u = (f32x2){bs2[s], bs2[s]};
#pragma unroll
            for (int t = 0; t < k; ++t) {
                const int st = 2 * j + off + t;
                const f32x2 p = (st & 1) ? xo[st >> 1] : xp[st >> 1];
                const f32x2 wv = (f32x2){w2[s][t], w2[s][t]};
                u = pkfma(wv, p, u);
            }
            f32x2 ev;
            ev.x = __builtin_amdgcn_exp2f(u.x);
            ev.y = __builtin_amdgcn_exp2f(u.y);
            Spk[s] += ev;
            Tpk[s] = pkfma(u, ev, Tpk[s]);
        }
    }

    // combine packed halves; mask lanes 60..63 (duplicates of 59)
    const bool active = lane < 60;
    float S[4], Tu[4];
#pragma unroll
    for (int s = 0; s < 4; ++s) {
        S[s]  = active ? (Spk[s].x + Spk[s].y) : 0.0f;
        Tu[s] = active ? (Tpk[s].x + Tpk[s].y) : 0.0f;
    }

    // wave totals via DPP; entropy = ln2 * (log2 S - Tu/S), wave-uniform
    float ent[4];
#pragma unroll
    for (int s = 0; s < 4; ++s) {
        float Sg = wave_sum64(S[s]);
        float Tg = wave_sum64(Tu[s]);
        ent[s] = LN2 * (__builtin_amdgcn_logf(Sg)
                        - Tg * __builtin_amdgcn_rcpf(Sg));
    }

    // MLP: hidden unit per lane (mod 32); logits via DPP 32-lane sums
    const int hidx = lane & 31;
    float h = b1[hidx];
#pragma unroll
    for (int s = 0; s < 4; ++s) h = fmaf(ent[s], W1[s * 32 + hidx], h);
    h = fmaxf(h, 0.0f);

    const float4 w2v = ((const float4*)W2)[hidx];
    float lg0 = half_sum32(h * w2v.x) + b2[0];
    float lg1 = half_sum32(h * w2v.y) + b2[1];
    float lg2 = half_sum32(h * w2v.z) + b2[2];
    float lg3 = half_sum32(h * w2v.w) + b2[3];

    // softmax (wave-uniform), LN2 folded into the mixing weights
    float m = fmaxf(fmaxf(lg0, lg1), fmaxf(lg2, lg3));
    float e0w = __expf(lg0 - m), e1w = __expf(lg1 - m);
    float e2w = __expf(lg2 - m), e3w = __expf(lg3 - m);
    float inv = LN2 / (e0w + e1w + e2w + e3w);
    const float wgt[4] = {e0w * inv, e1w * inv, e2w * inv, e3w * inv};

    // merged 9-tap output kernel (w2 are LOG2E-scaled; wgt carries the LN2)
    float Wm[9] = {0,0,0,0,0,0,0,0,0};
    float Bm = 0.f;
#pragma unroll
    for (int s = 0; s < 4; ++s) {
        const int k = 3 + 2 * s;
        const int off = 3 - s;
#pragma unroll
        for (int t = 0; t < k; ++t)
            Wm[off + t] = fmaf(wgt[s], w2[s][t], Wm[off + t]);
        Bm = fmaf(wgt[s], bs2[s], Bm);
    }

    // ---- packed output conv: pair (2j,2j+1) = (Bm,Bm) + sum_d Wm[d]*pair(2j+d)
    if (active) {
        float* __restrict__ orow = out + (size_t)row * L_LEN + 12 * lane;
        f32x2 o[6];
#pragma unroll
        for (int j = 0; j < 6; ++j) {
            f32x2 acc = (f32x2){Bm, Bm};
#pragma unroll
            for (int d = 0; d < 9; ++d) {
                const int st = 2 * j + d;
                const f32x2 p = (st & 1) ? xo[st >> 1] : xp[st >> 1];
                const f32x2 wv = (f32x2){Wm[d], Wm[d]};
                acc = pkfma(wv, p, acc);
            }
            o[j] = acc;
        }
#pragma unroll
        for (int q = 0; q < 3; ++q) {
            float4 v;
            v.x = o[2 * q].x;     v.y = o[2 * q].y;
            v.z = o[2 * q + 1].x; v.w = o[2 * q + 1].y;
            *(float4*)(orow + 4 * q) = v;
        }
    }
}

extern "C" void kernel_launch(void* const* d_in, const int* in_sizes, int n_in,
                              void* d_out, int out_size, void* d_ws, size_t ws_size,
                              hipStream_t stream) {
    const float* xp  = (const float*)d_in[0];
    const float* cw0 = (const float*)d_in[1];
    const float* cb0 = (const float*)d_in[2];
    const float* cw1 = (const float*)d_in[3];
    const float* cb1 = (const float*)d_in[4];
    const float* cw2 = (const float*)d_in[5];
    const float* cb2 = (const float*)d_in[6];
    const float* cw3 = (const float*)d_in[7];
    const float* cb3 = (const float*)d_in[8];
    const float* W1  = (const float*)d_in[9];
    const float* b1  = (const float*)d_in[10];
    const float* W2  = (const float*)d_in[11];
    const float* b2  = (const float*)d_in[12];
    float* outp = (float*)d_out;

    trend_kernel<<<NROWS, NT, 0, stream>>>(xp, cw0, cb0, cw1, cb1, cw2, cb2,
                                           cw3, cb3, W1, b1, W2, b2, outp);
}

// Round 15
// 32.957 us; speedup vs baseline: 1.2925x; 1.0194x over previous
//
#include <hip/hip_runtime.h>
#include <math.h>

#define NT 64
#define L_LEN 720
#define NROWS (64 * 321)   // 20544

#define LOG2E 1.4426950408889634f
#define LN2   0.6931471805599453f

typedef float f32x2 __attribute__((ext_vector_type(2)));

__device__ __forceinline__ f32x2 pkfma(f32x2 a, f32x2 b, f32x2 c) {
    return __builtin_elementwise_fma(a, b, c);   // -> v_pk_fma_f32
}

// uniform float -> SGPR (frees a VGPR; pkfma may read 1 SGPR operand)
__device__ __forceinline__ float rfl(float v) {
    return __int_as_float(__builtin_amdgcn_readfirstlane(__float_as_int(v)));
}

// ---- DPP wave reductions: pure VALU pipe, no LDS, no lgkmcnt stalls ----
template<int CTRL, int RM>
__device__ __forceinline__ float dpp_add(float x) {
    int t = __builtin_amdgcn_update_dpp(0, __float_as_int(x), CTRL, RM, 0xf, true);
    return x + __int_as_float(t);
}

__device__ __forceinline__ float wave_sum64(float x) {
    x = dpp_add<0x111, 0xf>(x);   // row_shr:1
    x = dpp_add<0x112, 0xf>(x);   // row_shr:2
    x = dpp_add<0x114, 0xf>(x);   // row_shr:4
    x = dpp_add<0x118, 0xf>(x);   // row_shr:8
    x = dpp_add<0x142, 0xa>(x);   // row_bcast:15 -> rows 1,3
    x = dpp_add<0x143, 0xc>(x);   // row_bcast:31 -> rows 2,3 ; lane63 = total
    return __int_as_float(__builtin_amdgcn_readlane(__float_as_int(x), 63));
}

__device__ __forceinline__ float half_sum32(float x) {
    x = dpp_add<0x111, 0xf>(x);
    x = dpp_add<0x112, 0xf>(x);
    x = dpp_add<0x114, 0xf>(x);
    x = dpp_add<0x118, 0xf>(x);
    x = dpp_add<0x142, 0xa>(x);   // lane31 = sum lanes 0..31
    return __int_as_float(__builtin_amdgcn_readlane(__float_as_int(x), 31));
}

__global__ __launch_bounds__(NT, 4) void trend_kernel(
    const float* __restrict__ x,
    const float* __restrict__ cw0, const float* __restrict__ cb0,
    const float* __restrict__ cw1, const float* __restrict__ cb1,
    const float* __restrict__ cw2, const float* __restrict__ cb2,
    const float* __restrict__ cw3, const float* __restrict__ cb3,
    const float* __restrict__ W1, const float* __restrict__ b1,
    const float* __restrict__ W2, const float* __restrict__ b2,
    float* __restrict__ out)
{
    // R14 base (1 wave/block, packed fp32, DPP reductions) +
    //  - conv outputs u kept in regs -> output = sum_s wgt'_s * u_s
    //    (deletes the 2nd conv and the Wm merge entirely)
    //  - stride-6 pair view p[i] = (xw[i], xw[i+6])
    //  - weights in SGPRs via readfirstlane (frees 40 VGPRs)
    const int lane = threadIdx.x;            // 0..63
    const int row  = blockIdx.x;

    const float* __restrict__ xr = x + (size_t)row * L_LEN;

    // ---- loads first (lanes 60..63 shadow lane 59; masked later)
    const int ll = (lane < 60) ? lane : 59;
    const int e0 = 12 * ll - 4;
    float xw[20];
#pragma unroll
    for (int q = 0; q < 5; ++q) {
        int e = e0 + 4 * q;
        e = (e < 0) ? 0 : ((e > L_LEN - 4) ? (L_LEN - 4) : e);   // 16B-aligned
        float4 v = *(const float4*)(xr + e);
        xw[4 * q + 0] = v.x; xw[4 * q + 1] = v.y;
        xw[4 * q + 2] = v.z; xw[4 * q + 3] = v.w;
    }

    // ---- uniform weights -> SGPRs under the load shadow (LOG2E pre-folded)
    const float* cws[4] = {cw0, cw1, cw2, cw3};
    const float* cbs[4] = {cb0, cb1, cb2, cb3};
    float w2[4][9], bs2[4];
#pragma unroll
    for (int s = 0; s < 4; ++s) {
        const int k = 3 + 2 * s;
        bs2[s] = rfl(cbs[s][0] * LOG2E);
#pragma unroll
        for (int t = 0; t < 9; ++t)
            w2[s][t] = (t < k) ? rfl(cws[s][t] * LOG2E) : 0.0f;
    }

    // row-edge zero padding
    if (lane == 0)  { xw[0] = 0.f; xw[1] = 0.f; xw[2] = 0.f; xw[3] = 0.f; }
    if (lane == 59) { xw[16] = 0.f; xw[17] = 0.f; xw[18] = 0.f; xw[19] = 0.f; }

    // pin window (loads happen exactly once)
#pragma unroll
    for (int t = 0; t < 20; ++t) asm volatile("" : "+v"(xw[t]));

    // ---- stride-6 pair view: p[i] = (xw[i], xw[i+6]), i = 0..13
    f32x2 p[14];
#pragma unroll
    for (int i = 0; i < 14; ++i) p[i] = (f32x2){xw[i], xw[i + 6]};

    // ---- fused pass: conv(u) kept in regs -> 2^u -> accumulate S, Tu
    // output pair (j, j+6); tap t of scale s reads p[j + off + t]
    f32x2 fu[4][6];
    f32x2 Spk[4] = {{0.f,0.f},{0.f,0.f},{0.f,0.f},{0.f,0.f}};
    f32x2 Tpk[4] = {{0.f,0.f},{0.f,0.f},{0.f,0.f},{0.f,0.f}};
#pragma unroll
    for (int j = 0; j < 6; ++j) {
#pragma unroll
        for (int s = 0; s < 4; ++s) {
            const int k = 3 + 2 * s;
            const int off = 3 - s;              // 4 - k/2
            f32x2 u = (f32x2){bs2[s], bs2[s]};
#pragma unroll
            for (int t = 0; t < k; ++t) {
                const f32x2 wv = (f32x2){w2[s][t], w2[s][t]};
                u = pkfma(wv, p[j + off + t], u);
            }
            fu[s][j] = u;
            f32x2 ev;
            ev.x = __builtin_amdgcn_exp2f(u.x);
            ev.y = __builtin_amdgcn_exp2f(u.y);
            Spk[s] += ev;
            Tpk[s] = pkfma(u, ev, Tpk[s]);
        }
    }

    // pin fu: conv computed exactly once (no remat through the tail)
#pragma unroll
    for (int s = 0; s < 4; ++s)
#pragma unroll
        for (int j = 0; j < 6; ++j) {
            asm volatile("" : "+v"(fu[s][j].x));
            asm volatile("" : "+v"(fu[s][j].y));
        }

    // combine packed halves; mask lanes 60..63 (duplicates of 59)
    const bool active = lane < 60;
    float S[4], Tu[4];
#pragma unroll
    for (int s = 0; s < 4; ++s) {
        S[s]  = active ? (Spk[s].x + Spk[s].y) : 0.0f;
        Tu[s] = active ? (Tpk[s].x + Tpk[s].y) : 0.0f;
    }

    // wave totals via DPP; entropy = ln2 * (log2 S - Tu/S), wave-uniform
    float ent[4];
#pragma unroll
    for (int s = 0; s < 4; ++s) {
        float Sg = wave_sum64(S[s]);
        float Tg = wave_sum64(Tu[s]);
        ent[s] = LN2 * (__builtin_amdgcn_logf(Sg)
                        - Tg * __builtin_amdgcn_rcpf(Sg));
    }

    // MLP: hidden unit per lane (mod 32); logits via DPP 32-lane sums
    const int hidx = lane & 31;
    float h = b1[hidx];
#pragma unroll
    for (int s = 0; s < 4; ++s) h = fmaf(ent[s], W1[s * 32 + hidx], h);
    h = fmaxf(h, 0.0f);

    const float4 w2v = ((const float4*)W2)[hidx];
    float lg0 = half_sum32(h * w2v.x) + b2[0];
    float lg1 = half_sum32(h * w2v.y) + b2[1];
    float lg2 = half_sum32(h * w2v.z) + b2[2];
    float lg3 = half_sum32(h * w2v.w) + b2[3];

    // softmax (wave-uniform); LN2 folded so wgt' applies directly to u:
    // out = sum_s wgt_s * f_s = ln2 * sum_s wgt_s * u_s
    float m = fmaxf(fmaxf(lg0, lg1), fmaxf(lg2, lg3));
    float e0w = __expf(lg0 - m), e1w = __expf(lg1 - m);
    float e2w = __expf(lg2 - m), e3w = __expf(lg3 - m);
    float inv = LN2 / (e0w + e1w + e2w + e3w);
    const float wg0 = e0w * inv, wg1 = e1w * inv;
    const float wg2 = e2w * inv, wg3 = e3w * inv;

    // ---- output directly from the kept u pairs: 4 pkfma per pair
    if (active) {
        f32x2 o[6];
#pragma unroll
        for (int j = 0; j < 6; ++j) {
            f32x2 acc = (f32x2){wg0, wg0} * fu[0][j];
            acc = pkfma((f32x2){wg1, wg1}, fu[1][j], acc);
            acc = pkfma((f32x2){wg2, wg2}, fu[2][j], acc);
            acc = pkfma((f32x2){wg3, wg3}, fu[3][j], acc);
            o[j] = acc;
        }
        // elements: j -> o[j].x (0..5), j+6 -> o[j].y (6..11); repack to float4
        float* __restrict__ orow = out + (size_t)row * L_LEN + 12 * lane;
        float4 v0 = {o[0].x, o[1].x, o[2].x, o[3].x};
        float4 v1 = {o[4].x, o[5].x, o[0].y, o[1].y};
        float4 v2 = {o[2].y, o[3].y, o[4].y, o[5].y};
        *(float4*)(orow)     = v0;
        *(float4*)(orow + 4) = v1;
        *(float4*)(orow + 8) = v2;
    }
}

extern "C" void kernel_launch(void* const* d_in, const int* in_sizes, int n_in,
                              void* d_out, int out_size, void* d_ws, size_t ws_size,
                              hipStream_t stream) {
    const float* xp  = (const float*)d_in[0];
    const float* cw0 = (const float*)d_in[1];
    const float* cb0 = (const float*)d_in[2];
    const float* cw1 = (const float*)d_in[3];
    const float* cb1 = (const float*)d_in[4];
    const float* cw2 = (const float*)d_in[5];
    const float* cb2 = (const float*)d_in[6];
    const float* cw3 = (const float*)d_in[7];
    const float* cb3 = (const float*)d_in[8];
    const float* W1  = (const float*)d_in[9];
    const float* b1  = (const float*)d_in[10];
    const float* W2  = (const float*)d_in[11];
    const float* b2  = (const float*)d_in[12];
    float* outp = (float*)d_out;

    trend_kernel<<<NROWS, NT, 0, stream>>>(xp, cw0, cb0, cw1, cb1, cw2, cb2,
                                           cw3, cb3, W1, b1, W2, b2, outp);
}